// Round 4
// baseline (1069.206 us; speedup 1.0000x reference)
//
#include <hip/hip_runtime.h>

// GCN 2-layer, bucket-partitioned LDS-atomic aggregation.
// N=100000, F_in=512, H=16, C=40, E=3200000.
//
// Algebra: with hs = dinv*(h) pre-scaled at the producer,
//   (A_hat h)[i] = dinv[i] * ( sum_{s in N(i)} hs[s] + hs[i] ).
// Layer2 aggregate-then-transform: A_hat(h2 W2) == (A_hat h2) W2.
// Edges are coarse-bucketed by dst>>6 (64 nodes/bucket); each bucket's
// aggregation runs in one block with an LDS f32 tile (no global atomics).

#define TPB 256
#define LOCB 6                      // 64 nodes per bucket
#define BSZ (1 << LOCB)

// ---------------------------------------------------------------- zero counts
__global__ void k_init(int* __restrict__ cnt, int n) {
    int i = blockIdx.x * TPB + threadIdx.x;
    if (i < n) cnt[i] = 0;
}

// ---------------------------------------------------------------- per-node in-degree histogram
__global__ void k_count(const int* __restrict__ dst, int* __restrict__ cnt, int E) {
    int e = blockIdx.x * TPB + threadIdx.x;
    if (e < E) atomicAdd(&cnt[dst[e]], 1);
}

__global__ void k_dinv(const int* __restrict__ cnt, float* __restrict__ dinv, int n) {
    int i = blockIdx.x * TPB + threadIdx.x;
    if (i < n) dinv[i] = rsqrtf((float)(cnt[i] + 1));   // +1 self loop
}

// ---------------------------------------------------------------- coarse bucket offsets (single block)
// coarse[b] = sum of cnt over bucket b's 64 nodes; exclusive scan -> boff, cursor.
__global__ __launch_bounds__(1024) void k_coarse(const int* __restrict__ cnt, int n,
                                                 int* __restrict__ boff,
                                                 int* __restrict__ cursor, int B) {
    __shared__ int s[2048];
    const int t = threadIdx.x;
    for (int i = t; i < 2048; i += 1024) {
        int sum = 0;
        if (i < B) {
            int base = i << LOCB;
            int end = min(base + BSZ, n);
            for (int j = base; j < end; ++j) sum += cnt[j];
        }
        s[i] = sum;
    }
    __syncthreads();
    // inclusive Hillis-Steele scan over 2048, 2 elements per thread
    for (int off = 1; off <= 1024; off <<= 1) {
        int a0 = (t >= off) ? s[t - off] : 0;
        int a1 = s[t + 1024 - off];
        __syncthreads();
        s[t] += a0;
        s[t + 1024] += a1;
        __syncthreads();
    }
    for (int i = t; i < 2048; i += 1024) {
        if (i < B) {
            int ex = (i == 0) ? 0 : s[i - 1];
            boff[i] = ex;
            cursor[(size_t)i * 16] = ex;    // cursors padded to 1/line
        }
        if (i == B) boff[B] = s[B - 1];
    }
}

// ---------------------------------------------------------------- partition edges into buckets (packed u32)
__global__ void k_part(const int* __restrict__ src, const int* __restrict__ dst,
                       int* __restrict__ cursor, unsigned* __restrict__ pk, int E) {
    int e = blockIdx.x * TPB + threadIdx.x;
    if (e >= E) return;
    int s = src[e], d = dst[e];
    int b = d >> LOCB;
    int slot = atomicAdd(&cursor[(size_t)b * 16], 1);
    pk[slot] = (unsigned)s | ((unsigned)(d & (BSZ - 1)) << 17);   // n < 2^17
}

// ---------------------------------------------------------------- GEMM1: hs1[n,16] = dinv * (x[n,512] @ W1)
#define G1_ROWS 256
#define G1_KC 32
__global__ __launch_bounds__(TPB) void k_gemm1(const float* __restrict__ x,
                                               const float* __restrict__ W,
                                               const float* __restrict__ dinv,
                                               float* __restrict__ hs, int n) {
    __shared__ float xs[G1_ROWS][36];
    __shared__ float wl[G1_KC][16];
    const int tid = threadIdx.x;
    const int row0 = blockIdx.x * G1_ROWS;
    const int rg = tid >> 2;            // 0..63
    const int c0 = (tid & 3) * 4;       // 0,4,8,12

    float acc[4][4];
#pragma unroll
    for (int j = 0; j < 4; ++j)
#pragma unroll
        for (int c = 0; c < 4; ++c) acc[j][c] = 0.0f;

    for (int kc = 0; kc < 512; kc += G1_KC) {
        __syncthreads();
#pragma unroll
        for (int t = 0; t < 8; ++t) {
            int f4 = tid + TPB * t;
            int row = f4 >> 3;
            int kk = (f4 & 7) * 4;
            int grow = row0 + row;
            if (grow >= n) grow = n - 1;
            float4 v = *reinterpret_cast<const float4*>(&x[(size_t)grow * 512 + kc + kk]);
            *reinterpret_cast<float4*>(&xs[row][kk]) = v;
        }
        if (tid < 128) {
            int k = tid >> 2, cc = (tid & 3) * 4;
            *reinterpret_cast<float4*>(&wl[k][cc]) =
                *reinterpret_cast<const float4*>(&W[(size_t)(kc + k) * 16 + cc]);
        }
        __syncthreads();

#pragma unroll
        for (int k4 = 0; k4 < G1_KC; k4 += 4) {
            float w[4][4];
#pragma unroll
            for (int kk = 0; kk < 4; ++kk) {
                float4 wv = *reinterpret_cast<const float4*>(&wl[k4 + kk][c0]);
                w[kk][0] = wv.x; w[kk][1] = wv.y; w[kk][2] = wv.z; w[kk][3] = wv.w;
            }
#pragma unroll
            for (int j = 0; j < 4; ++j) {
                float4 xv = *reinterpret_cast<const float4*>(&xs[rg + 64 * j][k4]);
                float xk[4] = {xv.x, xv.y, xv.z, xv.w};
#pragma unroll
                for (int kk = 0; kk < 4; ++kk)
#pragma unroll
                    for (int c = 0; c < 4; ++c) acc[j][c] += xk[kk] * w[kk][c];
            }
        }
    }

#pragma unroll
    for (int j = 0; j < 4; ++j) {
        int grow = row0 + rg + 64 * j;
        if (grow < n) {
            float di = dinv[grow];
            float4 v = make_float4(acc[j][0] * di, acc[j][1] * di,
                                   acc[j][2] * di, acc[j][3] * di);
            *reinterpret_cast<float4*>(&hs[(size_t)grow * 16 + c0]) = v;
        }
    }
}

// ---------------------------------------------------------------- bucket aggregation (LDS atomics)
// One block per bucket. tile[64 nodes][16 feats] (stride 17 to spread banks).
// L1 epilogue: hout = dinv * relu(dinv*(acc + self) + b)
// L2 epilogue: hout = dinv * (acc + self)
template <bool L1>
__global__ __launch_bounds__(TPB) void k_agg(const int* __restrict__ boff,
                                             const unsigned* __restrict__ pk,
                                             const float* __restrict__ hin,
                                             const float* __restrict__ dinv,
                                             const float* __restrict__ b1,
                                             float* __restrict__ hout, int n) {
    __shared__ float tile[BSZ * 17];
    const int tid = threadIdx.x;
    const int bkt = blockIdx.x;
    for (int i = tid; i < BSZ * 17; i += TPB) tile[i] = 0.0f;
    __syncthreads();

    const int r0 = boff[bkt], r1 = boff[bkt + 1];
    const int q4 = (tid >> 6) * 4;      // wave -> feature quad (0,4,8,12)
    const int eo = tid & 63;            // lane -> edge offset (coalesced pk reads)
    for (int j = r0 + eo; j < r1; j += 64) {
        unsigned p = pk[j];
        int s = p & 0x1FFFF;
        int l = (p >> 17) & (BSZ - 1);
        float4 v = *reinterpret_cast<const float4*>(&hin[(size_t)s * 16 + q4]);
        float* tp = &tile[l * 17 + q4];
        atomicAdd(&tp[0], v.x);
        atomicAdd(&tp[1], v.y);
        atomicAdd(&tp[2], v.z);
        atomicAdd(&tp[3], v.w);
    }
    __syncthreads();

    const int node0 = bkt << LOCB;
    for (int i = tid; i < BSZ * 16; i += TPB) {
        int l = i >> 4, f = i & 15;
        int node = node0 + l;
        if (node < n) {
            float di = dinv[node];
            float self = hin[(size_t)node * 16 + f];
            float pre = di * (tile[l * 17 + f] + self);
            if (L1) {
                float h = fmaxf(pre + b1[f], 0.0f);
                hout[(size_t)node * 16 + f] = di * h;
            } else {
                hout[(size_t)node * 16 + f] = pre;
            }
        }
    }
}

// ---------------------------------------------------------------- GEMM2: out[n,40] = pre2[n,16] @ W2 + b2
__global__ void k_gemm2f(const float* __restrict__ pre2, const float* __restrict__ W2,
                         const float* __restrict__ b2, float* __restrict__ out, int n) {
    __shared__ float wl[16 * 40];
    __shared__ float bl[40];
    int tid = threadIdx.x;
    for (int i = tid; i < 640; i += TPB) wl[i] = W2[i];
    if (tid < 40) bl[tid] = b2[tid];
    __syncthreads();
    int gid = blockIdx.x * TPB + tid;
    if (gid >= n * 40) return;
    int r = gid / 40, c = gid - r * 40;
    const float* pr = &pre2[(size_t)r * 16];
    float a = bl[c];
#pragma unroll
    for (int k = 0; k < 16; ++k) a += pr[k] * wl[k * 40 + c];
    out[gid] = a;
}

extern "C" void kernel_launch(void* const* d_in, const int* in_sizes, int n_in,
                              void* d_out, int out_size, void* d_ws, size_t ws_size,
                              hipStream_t stream) {
    const float* x  = (const float*)d_in[0];
    const int*   ei = (const int*)d_in[1];
    const float* W1 = (const float*)d_in[2];
    const float* b1 = (const float*)d_in[3];
    const float* W2 = (const float*)d_in[4];
    const float* b2 = (const float*)d_in[5];
    float* out = (float*)d_out;

    const int n = in_sizes[0] / 512;
    const int E = in_sizes[1] / 2;
    const int* src = ei;
    const int* dst = ei + E;
    const int B = (n + BSZ - 1) >> LOCB;         // 1563 buckets

    // workspace layout
    char* w = (char*)d_ws;
    int*      cnt    = (int*)w;       w += (size_t)n * 4;
    int*      boff   = (int*)w;       w += (size_t)(B + 1) * 4;
    int*      cursor = (int*)w;       w += (size_t)B * 16 * 4;   // padded 1/line
    unsigned* pk     = (unsigned*)w;  w += (size_t)E * 4;
    float*    dinv   = (float*)w;     w += (size_t)n * 4;
    float*    hs1    = (float*)w;     w += (size_t)n * 16 * 4;
    float*    hs2    = (float*)w;     w += (size_t)n * 16 * 4;
    float*    pre2   = (float*)w;     // n*16*4

    const int NBn = (n + TPB - 1) / TPB;
    const int NBe = (E + TPB - 1) / TPB;

    k_init  <<<NBn, TPB, 0, stream>>>(cnt, n);
    k_count <<<NBe, TPB, 0, stream>>>(dst, cnt, E);
    k_dinv  <<<NBn, TPB, 0, stream>>>(cnt, dinv, n);
    k_coarse<<<1, 1024, 0, stream>>>(cnt, n, boff, cursor, B);
    k_part  <<<NBe, TPB, 0, stream>>>(src, dst, cursor, pk, E);
    k_gemm1 <<<(n + G1_ROWS - 1) / G1_ROWS, TPB, 0, stream>>>(x, W1, dinv, hs1, n);
    k_agg<true>  <<<B, TPB, 0, stream>>>(boff, pk, hs1, dinv, b1, hs2, n);
    k_agg<false> <<<B, TPB, 0, stream>>>(boff, pk, hs2, dinv, b1, pre2, n);
    k_gemm2f<<<(n * 40 + TPB - 1) / TPB, TPB, 0, stream>>>(pre2, W2, b2, out, n);
}

// Round 5
// 468.005 us; speedup vs baseline: 2.2846x; 2.2846x over previous
//
#include <hip/hip_runtime.h>

// GCN 2-layer, exact-CSR gather aggregation (atomic-free aggs).
// N=100000, F_in=512, H=16, C=40, E=3200000.
//
// Algebra: with hs = dinv*h pre-scaled at the producer,
//   (A_hat h)[i] = dinv[i] * ( sum_{s in N(i)} hs[s] + hs[i] ).
// Layer2 aggregate-then-transform: A_hat(h2 W2) == (A_hat h2) W2.
// CSR fill uses XCD-affinity filtering: block bid only commits edges with
// (dst>>6)&7 == bid&7, so each CSR region is written from one XCD's L2 ->
// full-line writebacks (fixes the 194MB write amplification seen in R3).

#define TPB 256

// ---------------------------------------------------------------- zero counts
__global__ void k_init(int* __restrict__ cnt, int n) {
    int i = blockIdx.x * TPB + threadIdx.x;
    if (i < n) cnt[i] = 0;
}

// ---------------------------------------------------------------- per-node in-degree histogram
__global__ void k_count(const int* __restrict__ dst, int* __restrict__ cnt, int E) {
    int e = blockIdx.x * TPB + threadIdx.x;
    if (e < E) atomicAdd(&cnt[dst[e]], 1);
}

// ---------------------------------------------------------------- exclusive scan (3 kernels) + dinv
__global__ void k_scan1(const int* __restrict__ cnt, int* __restrict__ rs,
                        int* __restrict__ partials, float* __restrict__ dinv, int n) {
    __shared__ int s[TPB];
    int tid = threadIdx.x;
    int i = blockIdx.x * TPB + tid;
    int c = (i < n) ? cnt[i] : 0;
    if (i < n) dinv[i] = rsqrtf((float)(c + 1));   // +1 self loop
    s[tid] = c;
    __syncthreads();
#pragma unroll
    for (int off = 1; off < TPB; off <<= 1) {
        int t = (tid >= off) ? s[tid - off] : 0;
        __syncthreads();
        s[tid] += t;
        __syncthreads();
    }
    if (i < n) rs[i] = s[tid] - c;           // exclusive within block
    if (tid == TPB - 1) partials[blockIdx.x] = s[tid];
}

__global__ void k_scan2(int* __restrict__ partials, int nb) {
    __shared__ int s[512];
    int tid = threadIdx.x;
    int p = (tid < nb) ? partials[tid] : 0;
    s[tid] = p;
    __syncthreads();
#pragma unroll
    for (int off = 1; off < 512; off <<= 1) {
        int t = (tid >= off) ? s[tid - off] : 0;
        __syncthreads();
        s[tid] += t;
        __syncthreads();
    }
    if (tid < nb) partials[tid] = s[tid] - p; // exclusive block offsets
}

__global__ void k_scan3(int* __restrict__ rs, int* __restrict__ cursor,
                        const int* __restrict__ partials, int n, int E) {
    int i = blockIdx.x * TPB + threadIdx.x;
    if (i < n) {
        int v = rs[i] + partials[blockIdx.x];
        rs[i] = v;
        cursor[i] = v;
    }
    if (i == 0) rs[n] = E;
}

// ---------------------------------------------------------------- CSR fill, XCD-affinity filtered
// grid = 8 * nchunks; block handles chunk (bid>>3), commits only edges whose
// dst 64-node group is congruent to (bid&7) mod 8. Round-robin dispatch puts
// bid&7 on one XCD -> each CSR region written by a single XCD's L2.
#define FCH (TPB * 4)
__global__ void k_fill8(const int* __restrict__ src, const int* __restrict__ dst,
                        int* __restrict__ cursor, int* __restrict__ ssrc, int E) {
    const int grp = blockIdx.x & 7;
    const int base = (blockIdx.x >> 3) * FCH;
#pragma unroll
    for (int t = 0; t < 4; ++t) {
        int e = base + threadIdx.x + TPB * t;
        if (e < E) {
            int d = dst[e];
            if (((d >> 6) & 7) == grp) {
                int slot = atomicAdd(&cursor[d], 1);
                ssrc[slot] = src[e];
            }
        }
    }
}

// ---------------------------------------------------------------- GEMM1: hs1[n,16] = dinv * (x[n,512] @ W1)
#define G1_ROWS 256
#define G1_KC 32
__global__ __launch_bounds__(TPB) void k_gemm1(const float* __restrict__ x,
                                               const float* __restrict__ W,
                                               const float* __restrict__ dinv,
                                               float* __restrict__ hs, int n) {
    __shared__ float xs[G1_ROWS][36];
    __shared__ float wl[G1_KC][16];
    const int tid = threadIdx.x;
    const int row0 = blockIdx.x * G1_ROWS;
    const int rg = tid >> 2;            // 0..63
    const int c0 = (tid & 3) * 4;       // 0,4,8,12

    float acc[4][4];
#pragma unroll
    for (int j = 0; j < 4; ++j)
#pragma unroll
        for (int c = 0; c < 4; ++c) acc[j][c] = 0.0f;

    for (int kc = 0; kc < 512; kc += G1_KC) {
        __syncthreads();
#pragma unroll
        for (int t = 0; t < 8; ++t) {
            int f4 = tid + TPB * t;
            int row = f4 >> 3;
            int kk = (f4 & 7) * 4;
            int grow = row0 + row;
            if (grow >= n) grow = n - 1;
            float4 v = *reinterpret_cast<const float4*>(&x[(size_t)grow * 512 + kc + kk]);
            *reinterpret_cast<float4*>(&xs[row][kk]) = v;
        }
        if (tid < 128) {
            int k = tid >> 2, cc = (tid & 3) * 4;
            *reinterpret_cast<float4*>(&wl[k][cc]) =
                *reinterpret_cast<const float4*>(&W[(size_t)(kc + k) * 16 + cc]);
        }
        __syncthreads();

#pragma unroll
        for (int k4 = 0; k4 < G1_KC; k4 += 4) {
            float w[4][4];
#pragma unroll
            for (int kk = 0; kk < 4; ++kk) {
                float4 wv = *reinterpret_cast<const float4*>(&wl[k4 + kk][c0]);
                w[kk][0] = wv.x; w[kk][1] = wv.y; w[kk][2] = wv.z; w[kk][3] = wv.w;
            }
#pragma unroll
            for (int j = 0; j < 4; ++j) {
                float4 xv = *reinterpret_cast<const float4*>(&xs[rg + 64 * j][k4]);
                float xk[4] = {xv.x, xv.y, xv.z, xv.w};
#pragma unroll
                for (int kk = 0; kk < 4; ++kk)
#pragma unroll
                    for (int c = 0; c < 4; ++c) acc[j][c] += xk[kk] * w[kk][c];
            }
        }
    }

#pragma unroll
    for (int j = 0; j < 4; ++j) {
        int grow = row0 + rg + 64 * j;
        if (grow < n) {
            float di = dinv[grow];
            float4 v = make_float4(acc[j][0] * di, acc[j][1] * di,
                                   acc[j][2] * di, acc[j][3] * di);
            *reinterpret_cast<float4*>(&hs[(size_t)grow * 16 + c0]) = v;
        }
    }
}

// ---------------------------------------------------------------- gather-agg, one wave per node.
// Lane = (j8, f2): 8 edges in flight, 8 lanes x float2 per row (64B rows).
// L1: hout = dinv * relu( dinv*(sum + self) + b )   (pre-scaled for layer 2)
// L2: hout = dinv * (sum + self)
template <bool L1>
__global__ __launch_bounds__(TPB) void k_gagg(const int* __restrict__ rs,
                                              const int* __restrict__ ssrc,
                                              const float* __restrict__ hin,
                                              const float* __restrict__ dinv,
                                              const float* __restrict__ b1,
                                              float* __restrict__ hout, int n) {
    int node = blockIdx.x * 4 + (threadIdx.x >> 6);
    if (node >= n) return;
    const int lane = threadIdx.x & 63;
    const int j8 = lane >> 3;            // 0..7 edge sub-group
    const int f2 = lane & 7;             // float2 index within row
    const int r0 = rs[node], r1 = rs[node + 1];

    float ax = 0.0f, ay = 0.0f;
    for (int j = r0 + j8; j < r1; j += 8) {
        int s = ssrc[j];
        float2 v = *reinterpret_cast<const float2*>(&hin[(size_t)s * 16 + f2 * 2]);
        ax += v.x; ay += v.y;
    }
#pragma unroll
    for (int m = 8; m <= 32; m <<= 1) {
        ax += __shfl_xor(ax, m);
        ay += __shfl_xor(ay, m);
    }
    if (j8 == 0) {
        float di = dinv[node];
        float2 self = *reinterpret_cast<const float2*>(&hin[(size_t)node * 16 + f2 * 2]);
        float px = di * (ax + self.x);
        float py = di * (ay + self.y);
        if (L1) {
            px = di * fmaxf(px + b1[f2 * 2], 0.0f);
            py = di * fmaxf(py + b1[f2 * 2 + 1], 0.0f);
        }
        *reinterpret_cast<float2*>(&hout[(size_t)node * 16 + f2 * 2]) = make_float2(px, py);
    }
}

// ---------------------------------------------------------------- GEMM2: out[n,40] = pre2[n,16] @ W2 + b2
__global__ void k_gemm2f(const float* __restrict__ pre2, const float* __restrict__ W2,
                         const float* __restrict__ b2, float* __restrict__ out, int n) {
    __shared__ float wl[16 * 40];
    __shared__ float bl[40];
    int tid = threadIdx.x;
    for (int i = tid; i < 640; i += TPB) wl[i] = W2[i];
    if (tid < 40) bl[tid] = b2[tid];
    __syncthreads();
    int gid = blockIdx.x * TPB + tid;
    if (gid >= n * 40) return;
    int r = gid / 40, c = gid - r * 40;
    const float* pr = &pre2[(size_t)r * 16];
    float a = bl[c];
#pragma unroll
    for (int k = 0; k < 16; ++k) a += pr[k] * wl[k * 40 + c];
    out[gid] = a;
}

extern "C" void kernel_launch(void* const* d_in, const int* in_sizes, int n_in,
                              void* d_out, int out_size, void* d_ws, size_t ws_size,
                              hipStream_t stream) {
    const float* x  = (const float*)d_in[0];
    const int*   ei = (const int*)d_in[1];
    const float* W1 = (const float*)d_in[2];
    const float* b1 = (const float*)d_in[3];
    const float* W2 = (const float*)d_in[4];
    const float* b2 = (const float*)d_in[5];
    float* out = (float*)d_out;

    const int n = in_sizes[0] / 512;
    const int E = in_sizes[1] / 2;
    const int* src = ei;
    const int* dst = ei + E;
    const int NB = (n + TPB - 1) / TPB;          // scan blocks (391)

    // workspace layout
    char* w = (char*)d_ws;
    int*   cnt      = (int*)w;                 w += (size_t)n * 4;
    int*   rs       = (int*)w;                 w += (size_t)(n + 1) * 4;
    int*   cursor   = (int*)w;                 w += (size_t)n * 4;
    int*   partials = (int*)w;                 w += (size_t)(NB + 1) * 4;
    int*   ssrc     = (int*)w;                 w += (size_t)E * 4;
    float* dinv     = (float*)w;               w += (size_t)n * 4;
    float* hs1      = (float*)w;               w += (size_t)n * 16 * 4;
    float* hs2      = (float*)w;               w += (size_t)n * 16 * 4;
    float* pre2     = (float*)w;               // n*16*4

    const int NBe = (E + TPB - 1) / TPB;
    const int NCH = (E + FCH - 1) / FCH;         // fill chunks

    k_init <<<NB, TPB, 0, stream>>>(cnt, n);
    k_count<<<NBe, TPB, 0, stream>>>(dst, cnt, E);
    k_scan1<<<NB, TPB, 0, stream>>>(cnt, rs, partials, dinv, n);
    k_scan2<<<1, 512, 0, stream>>>(partials, NB);
    k_scan3<<<NB, TPB, 0, stream>>>(rs, cursor, partials, n, E);
    k_fill8<<<8 * NCH, TPB, 0, stream>>>(src, dst, cursor, ssrc, E);
    k_gemm1<<<(n + G1_ROWS - 1) / G1_ROWS, TPB, 0, stream>>>(x, W1, dinv, hs1, n);
    k_gagg<true>  <<<(n + 3) / 4, TPB, 0, stream>>>(rs, ssrc, hs1, dinv, b1, hs2, n);
    k_gagg<false> <<<(n + 3) / 4, TPB, 0, stream>>>(rs, ssrc, hs2, dinv, b1, pre2, n);
    k_gemm2f<<<(n * 40 + TPB - 1) / TPB, TPB, 0, stream>>>(pre2, W2, b2, out, n);
}

// Round 6
// 447.483 us; speedup vs baseline: 2.3894x; 1.0459x over previous
//
#include <hip/hip_runtime.h>

// GCN 2-layer, exact-CSR gather aggregation (atomic-free aggs).
// N=100000, F_in=512, H=16, C=40, E=3200000.
//
// Algebra: with hs = dinv*h pre-scaled at the producer,
//   (A_hat h)[i] = dinv[i] * ( sum_{s in N(i)} hs[s] + hs[i] ).
// Layer2 aggregate-then-transform: A_hat(h2 W2) == (A_hat h2) W2.
// CSR fill: XCD-affinity filtering (block bid&7 commits only dst-groups
// congruent to bid&7 mod 8) + NON-TEMPORAL edge reads so the streaming
// read traffic doesn't evict the partial store lines from L2 (R5 showed
// 174MB writeback for 12.8MB payload = read-pollution eviction).

#define TPB 256

// ---------------------------------------------------------------- zero counts
__global__ void k_init(int* __restrict__ cnt, int n) {
    int i = blockIdx.x * TPB + threadIdx.x;
    if (i < n) cnt[i] = 0;
}

// ---------------------------------------------------------------- per-node in-degree histogram
__global__ void k_count(const int* __restrict__ dst, int* __restrict__ cnt, int E) {
    int e = blockIdx.x * TPB + threadIdx.x;
    if (e < E) atomicAdd(&cnt[__builtin_nontemporal_load(&dst[e])], 1);
}

// ---------------------------------------------------------------- exclusive scan (3 kernels) + dinv
__global__ void k_scan1(const int* __restrict__ cnt, int* __restrict__ rs,
                        int* __restrict__ partials, float* __restrict__ dinv, int n) {
    __shared__ int s[TPB];
    int tid = threadIdx.x;
    int i = blockIdx.x * TPB + tid;
    int c = (i < n) ? cnt[i] : 0;
    if (i < n) dinv[i] = rsqrtf((float)(c + 1));   // +1 self loop
    s[tid] = c;
    __syncthreads();
#pragma unroll
    for (int off = 1; off < TPB; off <<= 1) {
        int t = (tid >= off) ? s[tid - off] : 0;
        __syncthreads();
        s[tid] += t;
        __syncthreads();
    }
    if (i < n) rs[i] = s[tid] - c;           // exclusive within block
    if (tid == TPB - 1) partials[blockIdx.x] = s[tid];
}

__global__ void k_scan2(int* __restrict__ partials, int nb) {
    __shared__ int s[512];
    int tid = threadIdx.x;
    int p = (tid < nb) ? partials[tid] : 0;
    s[tid] = p;
    __syncthreads();
#pragma unroll
    for (int off = 1; off < 512; off <<= 1) {
        int t = (tid >= off) ? s[tid - off] : 0;
        __syncthreads();
        s[tid] += t;
        __syncthreads();
    }
    if (tid < nb) partials[tid] = s[tid] - p; // exclusive block offsets
}

__global__ void k_scan3(int* __restrict__ rs, int* __restrict__ cursor,
                        const int* __restrict__ partials, int n, int E) {
    int i = blockIdx.x * TPB + threadIdx.x;
    if (i < n) {
        int v = rs[i] + partials[blockIdx.x];
        rs[i] = v;
        cursor[i] = v;
    }
    if (i == 0) rs[n] = E;
}

// ---------------------------------------------------------------- CSR fill, XCD-affinity + nt reads
#define FCH (TPB * 4)
__global__ void k_fill8(const int* __restrict__ src, const int* __restrict__ dst,
                        int* __restrict__ cursor, int* __restrict__ ssrc, int E) {
    const int grp = blockIdx.x & 7;
    const int base = (blockIdx.x >> 3) * FCH;
#pragma unroll
    for (int t = 0; t < 4; ++t) {
        int e = base + threadIdx.x + TPB * t;
        if (e < E) {
            int d = __builtin_nontemporal_load(&dst[e]);
            if (((d >> 6) & 7) == grp) {
                int s = __builtin_nontemporal_load(&src[e]);
                int slot = atomicAdd(&cursor[d], 1);
                ssrc[slot] = s;
            }
        }
    }
}

// ---------------------------------------------------------------- GEMM1: hs1[n,16] = dinv * (x[n,512] @ W1)
#define G1_ROWS 256
#define G1_KC 32
__global__ __launch_bounds__(TPB) void k_gemm1(const float* __restrict__ x,
                                               const float* __restrict__ W,
                                               const float* __restrict__ dinv,
                                               float* __restrict__ hs, int n) {
    __shared__ float xs[G1_ROWS][36];
    __shared__ float wl[G1_KC][16];
    const int tid = threadIdx.x;
    const int row0 = blockIdx.x * G1_ROWS;
    const int rg = tid >> 2;            // 0..63
    const int c0 = (tid & 3) * 4;       // 0,4,8,12

    float acc[4][4];
#pragma unroll
    for (int j = 0; j < 4; ++j)
#pragma unroll
        for (int c = 0; c < 4; ++c) acc[j][c] = 0.0f;

    for (int kc = 0; kc < 512; kc += G1_KC) {
        __syncthreads();
#pragma unroll
        for (int t = 0; t < 8; ++t) {
            int f4 = tid + TPB * t;
            int row = f4 >> 3;
            int kk = (f4 & 7) * 4;
            int grow = row0 + row;
            if (grow >= n) grow = n - 1;
            float4 v = *reinterpret_cast<const float4*>(&x[(size_t)grow * 512 + kc + kk]);
            *reinterpret_cast<float4*>(&xs[row][kk]) = v;
        }
        if (tid < 128) {
            int k = tid >> 2, cc = (tid & 3) * 4;
            *reinterpret_cast<float4*>(&wl[k][cc]) =
                *reinterpret_cast<const float4*>(&W[(size_t)(kc + k) * 16 + cc]);
        }
        __syncthreads();

#pragma unroll
        for (int k4 = 0; k4 < G1_KC; k4 += 4) {
            float w[4][4];
#pragma unroll
            for (int kk = 0; kk < 4; ++kk) {
                float4 wv = *reinterpret_cast<const float4*>(&wl[k4 + kk][c0]);
                w[kk][0] = wv.x; w[kk][1] = wv.y; w[kk][2] = wv.z; w[kk][3] = wv.w;
            }
#pragma unroll
            for (int j = 0; j < 4; ++j) {
                float4 xv = *reinterpret_cast<const float4*>(&xs[rg + 64 * j][k4]);
                float xk[4] = {xv.x, xv.y, xv.z, xv.w};
#pragma unroll
                for (int kk = 0; kk < 4; ++kk)
#pragma unroll
                    for (int c = 0; c < 4; ++c) acc[j][c] += xk[kk] * w[kk][c];
            }
        }
    }

#pragma unroll
    for (int j = 0; j < 4; ++j) {
        int grow = row0 + rg + 64 * j;
        if (grow < n) {
            float di = dinv[grow];
            float4 v = make_float4(acc[j][0] * di, acc[j][1] * di,
                                   acc[j][2] * di, acc[j][3] * di);
            *reinterpret_cast<float4*>(&hs[(size_t)grow * 16 + c0]) = v;
        }
    }
}

// ---------------------------------------------------------------- gather-agg, one wave per node.
// Lane = (j16, f4): 16 edges in flight, 4 lanes x float4 per row (64B rows).
// L1: hout = dinv * relu( dinv*(sum + self) + b )   (pre-scaled for layer 2)
// L2: hout = dinv * (sum + self)
template <bool L1>
__global__ __launch_bounds__(TPB) void k_gagg(const int* __restrict__ rs,
                                              const int* __restrict__ ssrc,
                                              const float* __restrict__ hin,
                                              const float* __restrict__ dinv,
                                              const float* __restrict__ b1,
                                              float* __restrict__ hout, int n) {
    int node = blockIdx.x * 4 + (threadIdx.x >> 6);
    if (node >= n) return;
    const int lane = threadIdx.x & 63;
    const int j16 = lane >> 2;           // 0..15 edge sub-group
    const int f4 = lane & 3;             // float4 index within row
    const int r0 = rs[node], r1 = rs[node + 1];

    float ax = 0.0f, ay = 0.0f, az = 0.0f, aw = 0.0f;
    for (int j = r0 + j16; j < r1; j += 16) {
        int s = ssrc[j];
        float4 v = *reinterpret_cast<const float4*>(&hin[(size_t)s * 16 + f4 * 4]);
        ax += v.x; ay += v.y; az += v.z; aw += v.w;
    }
#pragma unroll
    for (int m = 4; m <= 32; m <<= 1) {
        ax += __shfl_xor(ax, m);
        ay += __shfl_xor(ay, m);
        az += __shfl_xor(az, m);
        aw += __shfl_xor(aw, m);
    }
    if (j16 == 0) {
        float di = dinv[node];
        float4 self = *reinterpret_cast<const float4*>(&hin[(size_t)node * 16 + f4 * 4]);
        float px = di * (ax + self.x);
        float py = di * (ay + self.y);
        float pz = di * (az + self.z);
        float pw = di * (aw + self.w);
        if (L1) {
            px = di * fmaxf(px + b1[f4 * 4 + 0], 0.0f);
            py = di * fmaxf(py + b1[f4 * 4 + 1], 0.0f);
            pz = di * fmaxf(pz + b1[f4 * 4 + 2], 0.0f);
            pw = di * fmaxf(pw + b1[f4 * 4 + 3], 0.0f);
        }
        *reinterpret_cast<float4*>(&hout[(size_t)node * 16 + f4 * 4]) =
            make_float4(px, py, pz, pw);
    }
}

// ---------------------------------------------------------------- GEMM2: out[n,40] = pre2[n,16] @ W2 + b2
__global__ void k_gemm2f(const float* __restrict__ pre2, const float* __restrict__ W2,
                         const float* __restrict__ b2, float* __restrict__ out, int n) {
    __shared__ float wl[16 * 40];
    __shared__ float bl[40];
    int tid = threadIdx.x;
    for (int i = tid; i < 640; i += TPB) wl[i] = W2[i];
    if (tid < 40) bl[tid] = b2[tid];
    __syncthreads();
    int gid = blockIdx.x * TPB + tid;
    if (gid >= n * 40) return;
    int r = gid / 40, c = gid - r * 40;
    const float* pr = &pre2[(size_t)r * 16];
    float a = bl[c];
#pragma unroll
    for (int k = 0; k < 16; ++k) a += pr[k] * wl[k * 40 + c];
    out[gid] = a;
}

extern "C" void kernel_launch(void* const* d_in, const int* in_sizes, int n_in,
                              void* d_out, int out_size, void* d_ws, size_t ws_size,
                              hipStream_t stream) {
    const float* x  = (const float*)d_in[0];
    const int*   ei = (const int*)d_in[1];
    const float* W1 = (const float*)d_in[2];
    const float* b1 = (const float*)d_in[3];
    const float* W2 = (const float*)d_in[4];
    const float* b2 = (const float*)d_in[5];
    float* out = (float*)d_out;

    const int n = in_sizes[0] / 512;
    const int E = in_sizes[1] / 2;
    const int* src = ei;
    const int* dst = ei + E;
    const int NB = (n + TPB - 1) / TPB;          // scan blocks (391)

    // workspace layout
    char* w = (char*)d_ws;
    int*   cnt      = (int*)w;                 w += (size_t)n * 4;
    int*   rs       = (int*)w;                 w += (size_t)(n + 1) * 4;
    int*   cursor   = (int*)w;                 w += (size_t)n * 4;
    int*   partials = (int*)w;                 w += (size_t)(NB + 1) * 4;
    int*   ssrc     = (int*)w;                 w += (size_t)E * 4;
    float* dinv     = (float*)w;               w += (size_t)n * 4;
    float* hs1      = (float*)w;               w += (size_t)n * 16 * 4;
    float* hs2      = (float*)w;               w += (size_t)n * 16 * 4;
    float* pre2     = (float*)w;               // n*16*4

    const int NBe = (E + TPB - 1) / TPB;
    const int NCH = (E + FCH - 1) / FCH;         // fill chunks

    k_init <<<NB, TPB, 0, stream>>>(cnt, n);
    k_count<<<NBe, TPB, 0, stream>>>(dst, cnt, E);
    k_scan1<<<NB, TPB, 0, stream>>>(cnt, rs, partials, dinv, n);
    k_scan2<<<1, 512, 0, stream>>>(partials, NB);
    k_scan3<<<NB, TPB, 0, stream>>>(rs, cursor, partials, n, E);
    k_fill8<<<8 * NCH, TPB, 0, stream>>>(src, dst, cursor, ssrc, E);
    k_gemm1<<<(n + G1_ROWS - 1) / G1_ROWS, TPB, 0, stream>>>(x, W1, dinv, hs1, n);
    k_gagg<true>  <<<(n + 3) / 4, TPB, 0, stream>>>(rs, ssrc, hs1, dinv, b1, hs2, n);
    k_gagg<false> <<<(n + 3) / 4, TPB, 0, stream>>>(rs, ssrc, hs2, dinv, b1, pre2, n);
    k_gemm2f<<<(n * 40 + TPB - 1) / TPB, TPB, 0, stream>>>(pre2, W2, b2, out, n);
}

// Round 7
// 303.941 us; speedup vs baseline: 3.5178x; 1.4723x over previous
//
#include <hip/hip_runtime.h>

// GCN 2-layer, hierarchical counting-sort CSR + plane-split gather aggregation.
// N=100000, F_in=512, H=16, C=40, E=3200000.
//
// Algebra: with hs = dinv*h pre-scaled at the producer,
//   (A_hat h)[i] = dinv[i] * ( sum_{s in N(i)} hs[s] + hs[i] ).
// Layer2 aggregate-then-transform: A_hat(h2 W2) == (A_hat h2) W2.
//
// CSR build (all global IO coalesced by construction — R3/R5/R6 showed 4B
// random scatters amplify HBM writes 10-15x):
//   k_hist    : per-(block,bucket) histogram, bucket = dst>>8 (256 nodes).
//   k_scanrow : scan each bucket's counts across blocks.
//   k_scanbkt : scan bucket totals -> bucket base offsets.
//   k_part    : block-local counting sort in LDS, linear-order global writes.
//   k_part2   : one block per bucket; exact per-node sort in LDS; emits
//               ssrc, rs, dinv coalesced.
// Aggregation: feature-split planes hs[n][8] (3.2MB, fits 4MiB XCD L2) so
// random row gathers are L2 hits; 32 edges in flight per wave.

#define TPB 256
#define CHUNK 6144          // edges per k_part/k_hist block
#define NBKT_MAX 392        // buckets (100000>>8 = 391) padded
#define MAXB 10240          // max edges per bucket staged in LDS (avg 8184)

typedef unsigned int u32;

// ---------------------------------------------------------------- bucket histogram
__global__ __launch_bounds__(TPB) void k_hist(const int* __restrict__ dst,
                                              int* __restrict__ histT,
                                              int E, int nbkt) {
    __shared__ int hist[NBKT_MAX];
    const int tid = threadIdx.x, blk = blockIdx.x;
    for (int k = tid; k < NBKT_MAX; k += TPB) hist[k] = 0;
    __syncthreads();
    const int base = blk * CHUNK;
    const int m = min(CHUNK, E - base);
    for (int i = tid; i < m; i += TPB) {
        int d = __builtin_nontemporal_load(&dst[base + i]);
        atomicAdd(&hist[d >> 8], 1);
    }
    __syncthreads();
    for (int k = tid; k < nbkt; k += TPB) histT[blk * NBKT_MAX + k] = hist[k];
}

// ---------------------------------------------------------------- scan bucket rows across blocks
__global__ __launch_bounds__(512) void k_scanrow(int* __restrict__ histT,
                                                 int* __restrict__ rowtot,
                                                 int NB1) {
    __shared__ int s[1024];
    const int t = threadIdx.x, k = blockIdx.x;
    int v0 = (t < NB1) ? histT[t * NBKT_MAX + k] : 0;
    int v1 = (t + 512 < NB1) ? histT[(t + 512) * NBKT_MAX + k] : 0;
    s[t] = v0; s[t + 512] = v1;
    __syncthreads();
    for (int off = 1; off <= 512; off <<= 1) {
        int a0 = (t >= off) ? s[t - off] : 0;
        int a1 = s[t + 512 - off];
        __syncthreads();
        s[t] += a0;
        s[t + 512] += a1;
        __syncthreads();
    }
    if (t < NB1) histT[t * NBKT_MAX + k] = s[t] - v0;                 // exclusive
    if (t + 512 < NB1) histT[(t + 512) * NBKT_MAX + k] = s[t + 512] - v1;
    if (t == 0) rowtot[k] = s[1023];
}

// ---------------------------------------------------------------- scan bucket totals
__global__ __launch_bounds__(512) void k_scanbkt(const int* __restrict__ rowtot,
                                                 int* __restrict__ bktbase,
                                                 int* __restrict__ rs,
                                                 int nbkt, int n, int E) {
    __shared__ int s[512];
    const int t = threadIdx.x;
    int v = (t < nbkt) ? rowtot[t] : 0;
    s[t] = v;
    __syncthreads();
    for (int off = 1; off <= 256; off <<= 1) {
        int a = (t >= off) ? s[t - off] : 0;
        __syncthreads();
        s[t] += a;
        __syncthreads();
    }
    if (t < nbkt) bktbase[t] = s[t] - v;     // exclusive
    if (t == 0) { bktbase[nbkt] = E; rs[n] = E; }
}

// ---------------------------------------------------------------- partition into buckets (LDS sort, coalesced writes)
__global__ __launch_bounds__(TPB) void k_part(const int* __restrict__ src,
                                              const int* __restrict__ dst,
                                              const int* __restrict__ histT,
                                              const int* __restrict__ bktbase,
                                              u32* __restrict__ pk,
                                              int E, int nbkt) {
    __shared__ u32 sbuf[CHUNK];
    __shared__ int sslot[CHUNK];
    __shared__ int hist[512], gb[512], cur[512];
    __shared__ int s[512];
    const int tid = threadIdx.x, blk = blockIdx.x;
    const int base = blk * CHUNK;
    const int m = min(CHUNK, E - base);
    for (int k = tid; k < 512; k += TPB) { hist[k] = 0; cur[k] = 0; }
    __syncthreads();
    for (int i = tid; i < m; i += TPB) {
        int d = __builtin_nontemporal_load(&dst[base + i]);
        atomicAdd(&hist[d >> 8], 1);
    }
    __syncthreads();
    // inclusive scan of hist[0..512) with 256 threads, 2 elems each
    int c0v = hist[tid], c1v = hist[tid + 256];
    s[tid] = c0v; s[tid + 256] = c1v;
    __syncthreads();
    for (int off = 1; off <= 256; off <<= 1) {
        int a0 = (tid >= off) ? s[tid - off] : 0;
        int a1 = s[tid + 256 - off];
        __syncthreads();
        s[tid] += a0;
        s[tid + 256] += a1;
        __syncthreads();
    }
    hist[tid] = s[tid] - c0v;                 // exclusive local base
    hist[tid + 256] = s[tid + 256] - c1v;
    if (tid < nbkt) gb[tid] = bktbase[tid] + histT[blk * NBKT_MAX + tid];
    if (tid + 256 < nbkt) gb[tid + 256] = bktbase[tid + 256] + histT[blk * NBKT_MAX + tid + 256];
    __syncthreads();
    for (int i = tid; i < m; i += TPB) {
        int d = __builtin_nontemporal_load(&dst[base + i]);
        int sv = __builtin_nontemporal_load(&src[base + i]);
        int k = d >> 8;
        int r = atomicAdd(&cur[k], 1);
        int p = hist[k] + r;
        sbuf[p] = (u32)sv | ((u32)(d & 255) << 17);     // src 17 bits, dloc 8 bits
        sslot[p] = gb[k] + r;
    }
    __syncthreads();
    for (int p = tid; p < m; p += TPB) pk[sslot[p]] = sbuf[p];   // ascending runs
}

// ---------------------------------------------------------------- exact per-node sort within bucket
__global__ __launch_bounds__(TPB) void k_part2(const u32* __restrict__ pk,
                                               const int* __restrict__ bktbase,
                                               int* __restrict__ ssrc,
                                               int* __restrict__ rs,
                                               float* __restrict__ dinv,
                                               int n) {
    __shared__ u32 ebuf[MAXB];
    __shared__ int cnt[256], csum[256], s[256];
    const int t = threadIdx.x, b = blockIdx.x;
    const int r0 = bktbase[b], r1 = bktbase[b + 1];
    const int m = r1 - r0;
    cnt[t] = 0;
    __syncthreads();
    for (int i = t; i < m; i += TPB) {
        u32 v = pk[r0 + i];
        if (i < MAXB) ebuf[i] = v;
        atomicAdd(&cnt[(v >> 17) & 255], 1);
    }
    __syncthreads();
    int c = cnt[t];
    s[t] = c;
    __syncthreads();
    for (int off = 1; off <= 128; off <<= 1) {
        int a = (t >= off) ? s[t - off] : 0;
        __syncthreads();
        s[t] += a;
        __syncthreads();
    }
    int ex = s[t] - c;
    csum[t] = ex;
    int node = (b << 8) + t;
    if (node < n) {
        rs[node] = r0 + ex;
        dinv[node] = rsqrtf((float)(c + 1));   // +1 self loop
    }
    cnt[t] = 0;
    __syncthreads();
    for (int i = t; i < m; i += TPB) {
        u32 v = (i < MAXB) ? ebuf[i] : pk[r0 + i];
        int dl = (v >> 17) & 255;
        int r = atomicAdd(&cnt[dl], 1);
        ssrc[r0 + csum[dl] + r] = (int)(v & 0x1FFFF);   // hot 33KB range, L2-local
    }
}

// ---------------------------------------------------------------- GEMM1: hs[n,16] = dinv * (x @ W1), plane-split output
#define G1_ROWS 256
#define G1_KC 32
__global__ __launch_bounds__(TPB) void k_gemm1(const float* __restrict__ x,
                                               const float* __restrict__ W,
                                               const float* __restrict__ dinv,
                                               float* __restrict__ hsA,
                                               float* __restrict__ hsB, int n) {
    __shared__ float xs[G1_ROWS][36];
    __shared__ float wl[G1_KC][16];
    const int tid = threadIdx.x;
    const int row0 = blockIdx.x * G1_ROWS;
    const int rg = tid >> 2;            // 0..63
    const int c0 = (tid & 3) * 4;       // 0,4,8,12

    float acc[4][4];
#pragma unroll
    for (int j = 0; j < 4; ++j)
#pragma unroll
        for (int c = 0; c < 4; ++c) acc[j][c] = 0.0f;

    for (int kc = 0; kc < 512; kc += G1_KC) {
        __syncthreads();
#pragma unroll
        for (int t = 0; t < 8; ++t) {
            int f4 = tid + TPB * t;
            int row = f4 >> 3;
            int kk = (f4 & 7) * 4;
            int grow = row0 + row;
            if (grow >= n) grow = n - 1;
            float4 v = *reinterpret_cast<const float4*>(&x[(size_t)grow * 512 + kc + kk]);
            *reinterpret_cast<float4*>(&xs[row][kk]) = v;
        }
        if (tid < 128) {
            int k = tid >> 2, cc = (tid & 3) * 4;
            *reinterpret_cast<float4*>(&wl[k][cc]) =
                *reinterpret_cast<const float4*>(&W[(size_t)(kc + k) * 16 + cc]);
        }
        __syncthreads();

#pragma unroll
        for (int k4 = 0; k4 < G1_KC; k4 += 4) {
            float w[4][4];
#pragma unroll
            for (int kk = 0; kk < 4; ++kk) {
                float4 wv = *reinterpret_cast<const float4*>(&wl[k4 + kk][c0]);
                w[kk][0] = wv.x; w[kk][1] = wv.y; w[kk][2] = wv.z; w[kk][3] = wv.w;
            }
#pragma unroll
            for (int j = 0; j < 4; ++j) {
                float4 xv = *reinterpret_cast<const float4*>(&xs[rg + 64 * j][k4]);
                float xk[4] = {xv.x, xv.y, xv.z, xv.w};
#pragma unroll
                for (int kk = 0; kk < 4; ++kk)
#pragma unroll
                    for (int c = 0; c < 4; ++c) acc[j][c] += xk[kk] * w[kk][c];
            }
        }
    }

#pragma unroll
    for (int j = 0; j < 4; ++j) {
        int grow = row0 + rg + 64 * j;
        if (grow < n) {
            float di = dinv[grow];
            float4 v = make_float4(acc[j][0] * di, acc[j][1] * di,
                                   acc[j][2] * di, acc[j][3] * di);
            float* pl = (c0 < 8) ? hsA : hsB;
            *reinterpret_cast<float4*>(&pl[(size_t)grow * 8 + (c0 & 7)]) = v;
        }
    }
}

// ---------------------------------------------------------------- gather-agg over one 8-feature plane.
// Wave per node; lane = (j, f4): 32 edges in flight x 2 lanes (float4 each).
// L1: hout = dinv * relu( dinv*(sum + self) + b )   (pre-scaled for layer 2)
// L2: hout = dinv * (sum + self)
template <bool L1>
__global__ __launch_bounds__(TPB) void k_gagg(const int* __restrict__ rs,
                                              const int* __restrict__ ssrc,
                                              const float* __restrict__ hinP,
                                              const float* __restrict__ dinv,
                                              const float* __restrict__ bP,
                                              float* __restrict__ houtP, int n) {
    int node = blockIdx.x * 4 + (threadIdx.x >> 6);
    if (node >= n) return;
    const int lane = threadIdx.x & 63;
    const int j = lane >> 1;             // 0..31 edge sub-group
    const int f4 = lane & 1;             // float4 half of the 8-float row
    const int r0 = rs[node], r1 = rs[node + 1];

    float ax = 0.0f, ay = 0.0f, az = 0.0f, aw = 0.0f;
    for (int jj = r0 + j; jj < r1; jj += 32) {
        int sv = ssrc[jj];
        float4 v = *reinterpret_cast<const float4*>(&hinP[(size_t)sv * 8 + f4 * 4]);
        ax += v.x; ay += v.y; az += v.z; aw += v.w;
    }
#pragma unroll
    for (int mk = 2; mk <= 32; mk <<= 1) {
        ax += __shfl_xor(ax, mk);
        ay += __shfl_xor(ay, mk);
        az += __shfl_xor(az, mk);
        aw += __shfl_xor(aw, mk);
    }
    if (j == 0) {
        float di = dinv[node];
        float4 self = *reinterpret_cast<const float4*>(&hinP[(size_t)node * 8 + f4 * 4]);
        float px = di * (ax + self.x);
        float py = di * (ay + self.y);
        float pz = di * (az + self.z);
        float pw = di * (aw + self.w);
        if (L1) {
            px = di * fmaxf(px + bP[f4 * 4 + 0], 0.0f);
            py = di * fmaxf(py + bP[f4 * 4 + 1], 0.0f);
            pz = di * fmaxf(pz + bP[f4 * 4 + 2], 0.0f);
            pw = di * fmaxf(pw + bP[f4 * 4 + 3], 0.0f);
        }
        *reinterpret_cast<float4*>(&houtP[(size_t)node * 8 + f4 * 4]) =
            make_float4(px, py, pz, pw);
    }
}

// ---------------------------------------------------------------- GEMM2: out[n,40] = [p2A|p2B] @ W2 + b2
__global__ void k_gemm2f(const float* __restrict__ pA, const float* __restrict__ pB,
                         const float* __restrict__ W2, const float* __restrict__ b2,
                         float* __restrict__ out, int n) {
    __shared__ float wl[16 * 40];
    __shared__ float bl[40];
    int tid = threadIdx.x;
    for (int i = tid; i < 640; i += TPB) wl[i] = W2[i];
    if (tid < 40) bl[tid] = b2[tid];
    __syncthreads();
    int gid = blockIdx.x * TPB + tid;
    if (gid >= n * 40) return;
    int r = gid / 40, cc = gid - r * 40;
    const float* a0 = &pA[(size_t)r * 8];
    const float* a1 = &pB[(size_t)r * 8];
    float a = bl[cc];
#pragma unroll
    for (int k = 0; k < 8; ++k) a += a0[k] * wl[k * 40 + cc];
#pragma unroll
    for (int k = 0; k < 8; ++k) a += a1[k] * wl[(k + 8) * 40 + cc];
    out[gid] = a;
}

extern "C" void kernel_launch(void* const* d_in, const int* in_sizes, int n_in,
                              void* d_out, int out_size, void* d_ws, size_t ws_size,
                              hipStream_t stream) {
    const float* x  = (const float*)d_in[0];
    const int*   ei = (const int*)d_in[1];
    const float* W1 = (const float*)d_in[2];
    const float* b1 = (const float*)d_in[3];
    const float* W2 = (const float*)d_in[4];
    const float* b2 = (const float*)d_in[5];
    float* out = (float*)d_out;

    const int n = in_sizes[0] / 512;
    const int E = in_sizes[1] / 2;
    const int* src = ei;
    const int* dst = ei + E;
    const int nbkt = (n + 255) >> 8;              // 391
    const int NB1 = (E + CHUNK - 1) / CHUNK;      // 521

    // workspace layout
    char* w = (char*)d_ws;
    int*   histT   = (int*)w;     w += (size_t)NB1 * NBKT_MAX * 4;
    int*   rowtot  = (int*)w;     w += (size_t)NBKT_MAX * 4;
    int*   bktbase = (int*)w;     w += (size_t)(NBKT_MAX + 1) * 4;
    u32*   pk      = (u32*)w;     w += (size_t)E * 4;
    int*   ssrc    = (int*)w;     w += (size_t)E * 4;
    int*   rs      = (int*)w;     w += (size_t)(n + 1) * 4;
    float* dinv    = (float*)w;   w += (size_t)n * 4;
    float* h1A     = (float*)w;   w += (size_t)n * 8 * 4;
    float* h1B     = (float*)w;   w += (size_t)n * 8 * 4;
    float* h2A     = (float*)w;   w += (size_t)n * 8 * 4;
    float* h2B     = (float*)w;   w += (size_t)n * 8 * 4;
    float* p2A = h1A;             // layer-1 planes dead after L1 gather
    float* p2B = h1B;

    k_hist   <<<NB1, TPB, 0, stream>>>(dst, histT, E, nbkt);
    k_scanrow<<<nbkt, 512, 0, stream>>>(histT, rowtot, NB1);
    k_scanbkt<<<1, 512, 0, stream>>>(rowtot, bktbase, rs, nbkt, n, E);
    k_part   <<<NB1, TPB, 0, stream>>>(src, dst, histT, bktbase, pk, E, nbkt);
    k_part2  <<<nbkt, TPB, 0, stream>>>(pk, bktbase, ssrc, rs, dinv, n);
    k_gemm1  <<<(n + G1_ROWS - 1) / G1_ROWS, TPB, 0, stream>>>(x, W1, dinv, h1A, h1B, n);
    k_gagg<true>  <<<(n + 3) / 4, TPB, 0, stream>>>(rs, ssrc, h1A, dinv, b1,     h2A, n);
    k_gagg<true>  <<<(n + 3) / 4, TPB, 0, stream>>>(rs, ssrc, h1B, dinv, b1 + 8, h2B, n);
    k_gagg<false> <<<(n + 3) / 4, TPB, 0, stream>>>(rs, ssrc, h2A, dinv, b1, p2A, n);
    k_gagg<false> <<<(n + 3) / 4, TPB, 0, stream>>>(rs, ssrc, h2B, dinv, b1, p2B, n);
    k_gemm2f<<<(n * 40 + TPB - 1) / TPB, TPB, 0, stream>>>(p2A, p2B, W2, b2, out, n);
}

// Round 8
// 252.221 us; speedup vs baseline: 4.2392x; 1.2051x over previous
//
#include <hip/hip_runtime.h>
#include <hip/hip_bf16.h>

// GCN 2-layer, counting-sort CSR + bf16-plane gather aggregation.
// N=100000, F_in=512, H=16, C=40, E=3200000.
//
// Algebra: with hs = dinv*h pre-scaled at the producer,
//   (A_hat h)[i] = dinv[i] * ( sum_{s in N(i)} hs[s] + hs[i] ).
// Layer2 aggregate-then-transform: A_hat(h2 W2) == (A_hat h2) W2.
//
// hs tables are stored as bf16 [n][16] (3.2MB -> fits a 4MiB XCD L2), so each
// layer's edge gather is ONE pass reading 32B/edge; accumulation stays f32.
// CSR build identical to R7 (all global IO coalesced by construction).

#define TPB 256
#define CHUNK 6144          // edges per k_part/k_hist block
#define NBKT_MAX 392        // buckets (100000>>8 = 391) padded
#define MAXB 10240          // max edges per bucket staged in LDS (avg 8184)

typedef unsigned int u32;

__device__ __forceinline__ float bflo(u32 u) { return __uint_as_float(u << 16); }
__device__ __forceinline__ float bfhi(u32 u) { return __uint_as_float(u & 0xFFFF0000u); }
__device__ __forceinline__ unsigned short f2bf(float f) {
    __hip_bfloat16 h = __float2bfloat16(f);
    return *reinterpret_cast<unsigned short*>(&h);
}

// ---------------------------------------------------------------- bucket histogram
__global__ __launch_bounds__(TPB) void k_hist(const int* __restrict__ dst,
                                              int* __restrict__ histT,
                                              int E, int nbkt) {
    __shared__ int hist[NBKT_MAX];
    const int tid = threadIdx.x, blk = blockIdx.x;
    for (int k = tid; k < NBKT_MAX; k += TPB) hist[k] = 0;
    __syncthreads();
    const int base = blk * CHUNK;
    const int m = min(CHUNK, E - base);
    for (int i = tid; i < m; i += TPB) {
        int d = __builtin_nontemporal_load(&dst[base + i]);
        atomicAdd(&hist[d >> 8], 1);
    }
    __syncthreads();
    for (int k = tid; k < nbkt; k += TPB) histT[blk * NBKT_MAX + k] = hist[k];
}

// ---------------------------------------------------------------- scan bucket rows across blocks
__global__ __launch_bounds__(512) void k_scanrow(int* __restrict__ histT,
                                                 int* __restrict__ rowtot,
                                                 int NB1) {
    __shared__ int s[1024];
    const int t = threadIdx.x, k = blockIdx.x;
    int v0 = (t < NB1) ? histT[t * NBKT_MAX + k] : 0;
    int v1 = (t + 512 < NB1) ? histT[(t + 512) * NBKT_MAX + k] : 0;
    s[t] = v0; s[t + 512] = v1;
    __syncthreads();
    for (int off = 1; off <= 512; off <<= 1) {
        int a0 = (t >= off) ? s[t - off] : 0;
        int a1 = s[t + 512 - off];
        __syncthreads();
        s[t] += a0;
        s[t + 512] += a1;
        __syncthreads();
    }
    if (t < NB1) histT[t * NBKT_MAX + k] = s[t] - v0;                 // exclusive
    if (t + 512 < NB1) histT[(t + 512) * NBKT_MAX + k] = s[t + 512] - v1;
    if (t == 0) rowtot[k] = s[1023];
}

// ---------------------------------------------------------------- scan bucket totals
__global__ __launch_bounds__(512) void k_scanbkt(const int* __restrict__ rowtot,
                                                 int* __restrict__ bktbase,
                                                 int* __restrict__ rs,
                                                 int nbkt, int n, int E) {
    __shared__ int s[512];
    const int t = threadIdx.x;
    int v = (t < nbkt) ? rowtot[t] : 0;
    s[t] = v;
    __syncthreads();
    for (int off = 1; off <= 256; off <<= 1) {
        int a = (t >= off) ? s[t - off] : 0;
        __syncthreads();
        s[t] += a;
        __syncthreads();
    }
    if (t < nbkt) bktbase[t] = s[t] - v;     // exclusive
    if (t == 0) { bktbase[nbkt] = E; rs[n] = E; }
}

// ---------------------------------------------------------------- partition into buckets (LDS sort, coalesced writes)
__global__ __launch_bounds__(TPB) void k_part(const int* __restrict__ src,
                                              const int* __restrict__ dst,
                                              const int* __restrict__ histT,
                                              const int* __restrict__ bktbase,
                                              u32* __restrict__ pk,
                                              int E, int nbkt) {
    __shared__ u32 sbuf[CHUNK];
    __shared__ int sslot[CHUNK];
    __shared__ int hist[512], gb[512], cur[512];
    __shared__ int s[512];
    const int tid = threadIdx.x, blk = blockIdx.x;
    const int base = blk * CHUNK;
    const int m = min(CHUNK, E - base);
    for (int k = tid; k < 512; k += TPB) { hist[k] = 0; cur[k] = 0; }
    __syncthreads();
    for (int i = tid; i < m; i += TPB) {
        int d = __builtin_nontemporal_load(&dst[base + i]);
        atomicAdd(&hist[d >> 8], 1);
    }
    __syncthreads();
    int c0v = hist[tid], c1v = hist[tid + 256];
    s[tid] = c0v; s[tid + 256] = c1v;
    __syncthreads();
    for (int off = 1; off <= 256; off <<= 1) {
        int a0 = (tid >= off) ? s[tid - off] : 0;
        int a1 = s[tid + 256 - off];
        __syncthreads();
        s[tid] += a0;
        s[tid + 256] += a1;
        __syncthreads();
    }
    hist[tid] = s[tid] - c0v;                 // exclusive local base
    hist[tid + 256] = s[tid + 256] - c1v;
    if (tid < nbkt) gb[tid] = bktbase[tid] + histT[blk * NBKT_MAX + tid];
    if (tid + 256 < nbkt) gb[tid + 256] = bktbase[tid + 256] + histT[blk * NBKT_MAX + tid + 256];
    __syncthreads();
    for (int i = tid; i < m; i += TPB) {
        int d = __builtin_nontemporal_load(&dst[base + i]);
        int sv = __builtin_nontemporal_load(&src[base + i]);
        int k = d >> 8;
        int r = atomicAdd(&cur[k], 1);
        int p = hist[k] + r;
        sbuf[p] = (u32)sv | ((u32)(d & 255) << 17);     // src 17 bits, dloc 8 bits
        sslot[p] = gb[k] + r;
    }
    __syncthreads();
    for (int p = tid; p < m; p += TPB) pk[sslot[p]] = sbuf[p];   // ascending runs
}

// ---------------------------------------------------------------- exact per-node sort within bucket
__global__ __launch_bounds__(TPB) void k_part2(const u32* __restrict__ pk,
                                               const int* __restrict__ bktbase,
                                               int* __restrict__ ssrc,
                                               int* __restrict__ rs,
                                               float* __restrict__ dinv,
                                               int n) {
    __shared__ u32 ebuf[MAXB];
    __shared__ int cnt[256], csum[256], s[256];
    const int t = threadIdx.x, b = blockIdx.x;
    const int r0 = bktbase[b], r1 = bktbase[b + 1];
    const int m = r1 - r0;
    cnt[t] = 0;
    __syncthreads();
    for (int i = t; i < m; i += TPB) {
        u32 v = pk[r0 + i];
        if (i < MAXB) ebuf[i] = v;
        atomicAdd(&cnt[(v >> 17) & 255], 1);
    }
    __syncthreads();
    int c = cnt[t];
    s[t] = c;
    __syncthreads();
    for (int off = 1; off <= 128; off <<= 1) {
        int a = (t >= off) ? s[t - off] : 0;
        __syncthreads();
        s[t] += a;
        __syncthreads();
    }
    int ex = s[t] - c;
    csum[t] = ex;
    int node = (b << 8) + t;
    if (node < n) {
        rs[node] = r0 + ex;
        dinv[node] = rsqrtf((float)(c + 1));   // +1 self loop
    }
    cnt[t] = 0;
    __syncthreads();
    for (int i = t; i < m; i += TPB) {
        u32 v = (i < MAXB) ? ebuf[i] : pk[r0 + i];
        int dl = (v >> 17) & 255;
        int r = atomicAdd(&cnt[dl], 1);
        ssrc[r0 + csum[dl] + r] = (int)(v & 0x1FFFF);   // hot 33KB range, L2-local
    }
}

// ---------------------------------------------------------------- GEMM1: hs1b[n,16](bf16) = dinv * (x @ W1)
#define G1_ROWS 256
#define G1_KC 32
__global__ __launch_bounds__(TPB) void k_gemm1(const float* __restrict__ x,
                                               const float* __restrict__ W,
                                               const float* __restrict__ dinv,
                                               unsigned short* __restrict__ hsb, int n) {
    __shared__ float xs[G1_ROWS][36];
    __shared__ float wl[G1_KC][16];
    const int tid = threadIdx.x;
    const int row0 = blockIdx.x * G1_ROWS;
    const int rg = tid >> 2;            // 0..63
    const int c0 = (tid & 3) * 4;       // 0,4,8,12

    float acc[4][4];
#pragma unroll
    for (int j = 0; j < 4; ++j)
#pragma unroll
        for (int c = 0; c < 4; ++c) acc[j][c] = 0.0f;

    for (int kc = 0; kc < 512; kc += G1_KC) {
        __syncthreads();
#pragma unroll
        for (int t = 0; t < 8; ++t) {
            int f4 = tid + TPB * t;
            int row = f4 >> 3;
            int kk = (f4 & 7) * 4;
            int grow = row0 + row;
            if (grow >= n) grow = n - 1;
            float4 v = *reinterpret_cast<const float4*>(&x[(size_t)grow * 512 + kc + kk]);
            *reinterpret_cast<float4*>(&xs[row][kk]) = v;
        }
        if (tid < 128) {
            int k = tid >> 2, cc = (tid & 3) * 4;
            *reinterpret_cast<float4*>(&wl[k][cc]) =
                *reinterpret_cast<const float4*>(&W[(size_t)(kc + k) * 16 + cc]);
        }
        __syncthreads();

#pragma unroll
        for (int k4 = 0; k4 < G1_KC; k4 += 4) {
            float w[4][4];
#pragma unroll
            for (int kk = 0; kk < 4; ++kk) {
                float4 wv = *reinterpret_cast<const float4*>(&wl[k4 + kk][c0]);
                w[kk][0] = wv.x; w[kk][1] = wv.y; w[kk][2] = wv.z; w[kk][3] = wv.w;
            }
#pragma unroll
            for (int j = 0; j < 4; ++j) {
                float4 xv = *reinterpret_cast<const float4*>(&xs[rg + 64 * j][k4]);
                float xk[4] = {xv.x, xv.y, xv.z, xv.w};
#pragma unroll
                for (int kk = 0; kk < 4; ++kk)
#pragma unroll
                    for (int c = 0; c < 4; ++c) acc[j][c] += xk[kk] * w[kk][c];
            }
        }
    }

#pragma unroll
    for (int j = 0; j < 4; ++j) {
        int grow = row0 + rg + 64 * j;
        if (grow < n) {
            float di = dinv[grow];
            ushort4 o;
            o.x = f2bf(acc[j][0] * di);
            o.y = f2bf(acc[j][1] * di);
            o.z = f2bf(acc[j][2] * di);
            o.w = f2bf(acc[j][3] * di);
            *reinterpret_cast<ushort4*>(&hsb[(size_t)grow * 16 + c0]) = o;
        }
    }
}

// ---------------------------------------------------------------- gather-agg, bf16 rows (32B), one pass per layer.
// Wave per node; lane = (j, hf): 32 edges in flight x 2 lanes (16B = 8 bf16 each).
// L1: houtB = bf16( dinv * relu( dinv*(sum+self) + b ) )   (pre-scaled for layer 2)
// L2: houtF = f32( dinv * (sum+self) )
template <bool L1>
__global__ __launch_bounds__(TPB) void k_gagg(const int* __restrict__ rs,
                                              const int* __restrict__ ssrc,
                                              const unsigned short* __restrict__ hinB,
                                              const float* __restrict__ dinv,
                                              const float* __restrict__ b1,
                                              unsigned short* __restrict__ houtB,
                                              float* __restrict__ houtF, int n) {
    int node = blockIdx.x * 4 + (threadIdx.x >> 6);
    if (node >= n) return;
    const int lane = threadIdx.x & 63;
    const int j = lane >> 1;             // 0..31 edge sub-group
    const int hf = lane & 1;             // which 8-feature half (16B)
    const int r0 = rs[node], r1 = rs[node + 1];

    float a[8];
#pragma unroll
    for (int q = 0; q < 8; ++q) a[q] = 0.0f;

    for (int e = r0 + j; e < r1; e += 32) {
        int sv = ssrc[e];
        uint4 v = *reinterpret_cast<const uint4*>(&hinB[(size_t)sv * 16 + hf * 8]);
        a[0] += bflo(v.x); a[1] += bfhi(v.x);
        a[2] += bflo(v.y); a[3] += bfhi(v.y);
        a[4] += bflo(v.z); a[5] += bfhi(v.z);
        a[6] += bflo(v.w); a[7] += bfhi(v.w);
    }
#pragma unroll
    for (int m = 2; m <= 32; m <<= 1)
#pragma unroll
        for (int q = 0; q < 8; ++q) a[q] += __shfl_xor(a[q], m);

    if (j == 0) {
        float di = dinv[node];
        uint4 sv = *reinterpret_cast<const uint4*>(&hinB[(size_t)node * 16 + hf * 8]);
        float sf[8] = {bflo(sv.x), bfhi(sv.x), bflo(sv.y), bfhi(sv.y),
                       bflo(sv.z), bfhi(sv.z), bflo(sv.w), bfhi(sv.w)};
        if (L1) {
            unsigned short ob[8];
#pragma unroll
            for (int q = 0; q < 8; ++q) {
                float p = di * (a[q] + sf[q]);
                ob[q] = f2bf(di * fmaxf(p + b1[hf * 8 + q], 0.0f));
            }
            uint4 ov;
            ov.x = (u32)ob[0] | ((u32)ob[1] << 16);
            ov.y = (u32)ob[2] | ((u32)ob[3] << 16);
            ov.z = (u32)ob[4] | ((u32)ob[5] << 16);
            ov.w = (u32)ob[6] | ((u32)ob[7] << 16);
            *reinterpret_cast<uint4*>(&houtB[(size_t)node * 16 + hf * 8]) = ov;
        } else {
            float4 o0, o1;
            o0.x = di * (a[0] + sf[0]); o0.y = di * (a[1] + sf[1]);
            o0.z = di * (a[2] + sf[2]); o0.w = di * (a[3] + sf[3]);
            o1.x = di * (a[4] + sf[4]); o1.y = di * (a[5] + sf[5]);
            o1.z = di * (a[6] + sf[6]); o1.w = di * (a[7] + sf[7]);
            float* op = &houtF[(size_t)node * 16 + hf * 8];
            *reinterpret_cast<float4*>(op) = o0;
            *reinterpret_cast<float4*>(op + 4) = o1;
        }
    }
}

// ---------------------------------------------------------------- GEMM2: out[n,40] = pre2[n,16] @ W2 + b2
__global__ void k_gemm2f(const float* __restrict__ pre2, const float* __restrict__ W2,
                         const float* __restrict__ b2, float* __restrict__ out, int n) {
    __shared__ float wl[16 * 40];
    __shared__ float bl[40];
    int tid = threadIdx.x;
    for (int i = tid; i < 640; i += TPB) wl[i] = W2[i];
    if (tid < 40) bl[tid] = b2[tid];
    __syncthreads();
    int gid = blockIdx.x * TPB + tid;
    if (gid >= n * 40) return;
    int r = gid / 40, cc = gid - r * 40;
    const float* pr = &pre2[(size_t)r * 16];
    float a = bl[cc];
#pragma unroll
    for (int k = 0; k < 16; ++k) a += pr[k] * wl[k * 40 + cc];
    out[gid] = a;
}

extern "C" void kernel_launch(void* const* d_in, const int* in_sizes, int n_in,
                              void* d_out, int out_size, void* d_ws, size_t ws_size,
                              hipStream_t stream) {
    const float* x  = (const float*)d_in[0];
    const int*   ei = (const int*)d_in[1];
    const float* W1 = (const float*)d_in[2];
    const float* b1 = (const float*)d_in[3];
    const float* W2 = (const float*)d_in[4];
    const float* b2 = (const float*)d_in[5];
    float* out = (float*)d_out;

    const int n = in_sizes[0] / 512;
    const int E = in_sizes[1] / 2;
    const int* src = ei;
    const int* dst = ei + E;
    const int nbkt = (n + 255) >> 8;              // 391
    const int NB1 = (E + CHUNK - 1) / CHUNK;      // 521

    // workspace layout
    char* w = (char*)d_ws;
    int*   histT   = (int*)w;     w += (size_t)NB1 * NBKT_MAX * 4;
    int*   rowtot  = (int*)w;     w += (size_t)NBKT_MAX * 4;
    int*   bktbase = (int*)w;     w += (size_t)(NBKT_MAX + 1) * 4;
    u32*   pk      = (u32*)w;     w += (size_t)E * 4;
    int*   ssrc    = (int*)w;     w += (size_t)E * 4;
    int*   rs      = (int*)w;     w += (size_t)(n + 1) * 4;
    float* dinv    = (float*)w;   w += (size_t)n * 4;
    unsigned short* h1b = (unsigned short*)w;  w += (size_t)n * 16 * 2;
    unsigned short* h2b = (unsigned short*)w;  w += (size_t)n * 16 * 2;
    float* pre2    = (float*)w;   // n*16*4

    k_hist   <<<NB1, TPB, 0, stream>>>(dst, histT, E, nbkt);
    k_scanrow<<<nbkt, 512, 0, stream>>>(histT, rowtot, NB1);
    k_scanbkt<<<1, 512, 0, stream>>>(rowtot, bktbase, rs, nbkt, n, E);
    k_part   <<<NB1, TPB, 0, stream>>>(src, dst, histT, bktbase, pk, E, nbkt);
    k_part2  <<<nbkt, TPB, 0, stream>>>(pk, bktbase, ssrc, rs, dinv, n);
    k_gemm1  <<<(n + G1_ROWS - 1) / G1_ROWS, TPB, 0, stream>>>(x, W1, dinv, h1b, n);
    k_gagg<true>  <<<(n + 3) / 4, TPB, 0, stream>>>(rs, ssrc, h1b, dinv, b1, h2b, nullptr, n);
    k_gagg<false> <<<(n + 3) / 4, TPB, 0, stream>>>(rs, ssrc, h2b, dinv, b1, nullptr, pre2, n);
    k_gemm2f<<<(n * 40 + TPB - 1) / TPB, TPB, 0, stream>>>(pre2, W2, b2, out, n);
}

// Round 9
// 241.294 us; speedup vs baseline: 4.4311x; 1.0453x over previous
//
#include <hip/hip_runtime.h>
#include <hip/hip_bf16.h>

// GCN 2-layer, counting-sort CSR + bf16-plane gather aggregation.
// N=100000, F_in=512, H=16, C=40, E=3200000.
//
// Algebra: with hs = dinv*h pre-scaled at the producer,
//   (A_hat h)[i] = dinv[i] * ( sum_{s in N(i)} hs[s] + hs[i] ).
// Layer2 aggregate-then-transform: A_hat(h2 W2) == (A_hat h2) W2.
//
// hs tables are bf16 [n][16] (3.2MB -> fits a 4MiB XCD L2); each layer's edge
// gather is ONE pass reading 32B/edge; accumulation stays f32.
// CSR build: hist -> scan -> LDS-sorted partition -> per-bucket exact sort,
// all global IO coalesced by construction (random 4B scatters amplify HBM
// writes 10-15x; measured R3/R5/R6).
// R9: GEMM2 fused into the layer-2 gather; x streamed non-temporally in gemm1
// so the gather tables / edge lists stay L2-resident; nt dropped in the sort
// so k_part's second dst read hits L2.

#define TPB 256
#define CHUNK 6144          // edges per k_part/k_hist block
#define NBKT_MAX 392        // buckets (100000>>8 = 391) padded
#define MAXB 10240          // max edges per bucket staged in LDS (avg 8184)

typedef unsigned int u32;
typedef float __attribute__((ext_vector_type(4))) f32x4;

__device__ __forceinline__ float bflo(u32 u) { return __uint_as_float(u << 16); }
__device__ __forceinline__ float bfhi(u32 u) { return __uint_as_float(u & 0xFFFF0000u); }
__device__ __forceinline__ unsigned short f2bf(float f) {
    __hip_bfloat16 h = __float2bfloat16(f);
    return *reinterpret_cast<unsigned short*>(&h);
}

// ---------------------------------------------------------------- bucket histogram
__global__ __launch_bounds__(TPB) void k_hist(const int* __restrict__ dst,
                                              int* __restrict__ histT,
                                              int E, int nbkt) {
    __shared__ int hist[NBKT_MAX];
    const int tid = threadIdx.x, blk = blockIdx.x;
    for (int k = tid; k < NBKT_MAX; k += TPB) hist[k] = 0;
    __syncthreads();
    const int base = blk * CHUNK;
    const int m = min(CHUNK, E - base);
    for (int i = tid; i < m; i += TPB) {
        int d = dst[base + i];
        atomicAdd(&hist[d >> 8], 1);
    }
    __syncthreads();
    for (int k = tid; k < nbkt; k += TPB) histT[blk * NBKT_MAX + k] = hist[k];
}

// ---------------------------------------------------------------- scan bucket rows across blocks
__global__ __launch_bounds__(512) void k_scanrow(int* __restrict__ histT,
                                                 int* __restrict__ rowtot,
                                                 int NB1) {
    __shared__ int s[1024];
    const int t = threadIdx.x, k = blockIdx.x;
    int v0 = (t < NB1) ? histT[t * NBKT_MAX + k] : 0;
    int v1 = (t + 512 < NB1) ? histT[(t + 512) * NBKT_MAX + k] : 0;
    s[t] = v0; s[t + 512] = v1;
    __syncthreads();
    for (int off = 1; off <= 512; off <<= 1) {
        int a0 = (t >= off) ? s[t - off] : 0;
        int a1 = s[t + 512 - off];
        __syncthreads();
        s[t] += a0;
        s[t + 512] += a1;
        __syncthreads();
    }
    if (t < NB1) histT[t * NBKT_MAX + k] = s[t] - v0;                 // exclusive
    if (t + 512 < NB1) histT[(t + 512) * NBKT_MAX + k] = s[t + 512] - v1;
    if (t == 0) rowtot[k] = s[1023];
}

// ---------------------------------------------------------------- scan bucket totals
__global__ __launch_bounds__(512) void k_scanbkt(const int* __restrict__ rowtot,
                                                 int* __restrict__ bktbase,
                                                 int* __restrict__ rs,
                                                 int nbkt, int n, int E) {
    __shared__ int s[512];
    const int t = threadIdx.x;
    int v = (t < nbkt) ? rowtot[t] : 0;
    s[t] = v;
    __syncthreads();
    for (int off = 1; off <= 256; off <<= 1) {
        int a = (t >= off) ? s[t - off] : 0;
        __syncthreads();
        s[t] += a;
        __syncthreads();
    }
    if (t < nbkt) bktbase[t] = s[t] - v;     // exclusive
    if (t == 0) { bktbase[nbkt] = E; rs[n] = E; }
}

// ---------------------------------------------------------------- partition into buckets (LDS sort, coalesced writes)
__global__ __launch_bounds__(TPB) void k_part(const int* __restrict__ src,
                                              const int* __restrict__ dst,
                                              const int* __restrict__ histT,
                                              const int* __restrict__ bktbase,
                                              u32* __restrict__ pk,
                                              int E, int nbkt) {
    __shared__ u32 sbuf[CHUNK];
    __shared__ int sslot[CHUNK];
    __shared__ int hist[512], gb[512], cur[512];
    __shared__ int s[512];
    const int tid = threadIdx.x, blk = blockIdx.x;
    const int base = blk * CHUNK;
    const int m = min(CHUNK, E - base);
    for (int k = tid; k < 512; k += TPB) { hist[k] = 0; cur[k] = 0; }
    __syncthreads();
    for (int i = tid; i < m; i += TPB) {
        int d = dst[base + i];                 // allocates L2; re-read below hits
        atomicAdd(&hist[d >> 8], 1);
    }
    __syncthreads();
    int c0v = hist[tid], c1v = hist[tid + 256];
    s[tid] = c0v; s[tid + 256] = c1v;
    __syncthreads();
    for (int off = 1; off <= 256; off <<= 1) {
        int a0 = (tid >= off) ? s[tid - off] : 0;
        int a1 = s[tid + 256 - off];
        __syncthreads();
        s[tid] += a0;
        s[tid + 256] += a1;
        __syncthreads();
    }
    hist[tid] = s[tid] - c0v;                 // exclusive local base
    hist[tid + 256] = s[tid + 256] - c1v;
    if (tid < nbkt) gb[tid] = bktbase[tid] + histT[blk * NBKT_MAX + tid];
    if (tid + 256 < nbkt) gb[tid + 256] = bktbase[tid + 256] + histT[blk * NBKT_MAX + tid + 256];
    __syncthreads();
    for (int i = tid; i < m; i += TPB) {
        int d = dst[base + i];
        int sv = src[base + i];
        int k = d >> 8;
        int r = atomicAdd(&cur[k], 1);
        int p = hist[k] + r;
        sbuf[p] = (u32)sv | ((u32)(d & 255) << 17);     // src 17 bits, dloc 8 bits
        sslot[p] = gb[k] + r;
    }
    __syncthreads();
    for (int p = tid; p < m; p += TPB) pk[sslot[p]] = sbuf[p];   // ascending runs
}

// ---------------------------------------------------------------- exact per-node sort within bucket
__global__ __launch_bounds__(TPB) void k_part2(const u32* __restrict__ pk,
                                               const int* __restrict__ bktbase,
                                               int* __restrict__ ssrc,
                                               int* __restrict__ rs,
                                               float* __restrict__ dinv,
                                               int n) {
    __shared__ u32 ebuf[MAXB];
    __shared__ int cnt[256], csum[256], s[256];
    const int t = threadIdx.x, b = blockIdx.x;
    const int r0 = bktbase[b], r1 = bktbase[b + 1];
    const int m = r1 - r0;
    cnt[t] = 0;
    __syncthreads();
    for (int i = t; i < m; i += TPB) {
        u32 v = pk[r0 + i];
        if (i < MAXB) ebuf[i] = v;
        atomicAdd(&cnt[(v >> 17) & 255], 1);
    }
    __syncthreads();
    int c = cnt[t];
    s[t] = c;
    __syncthreads();
    for (int off = 1; off <= 128; off <<= 1) {
        int a = (t >= off) ? s[t - off] : 0;
        __syncthreads();
        s[t] += a;
        __syncthreads();
    }
    int ex = s[t] - c;
    csum[t] = ex;
    int node = (b << 8) + t;
    if (node < n) {
        rs[node] = r0 + ex;
        dinv[node] = rsqrtf((float)(c + 1));   // +1 self loop
    }
    cnt[t] = 0;
    __syncthreads();
    for (int i = t; i < m; i += TPB) {
        u32 v = (i < MAXB) ? ebuf[i] : pk[r0 + i];
        int dl = (v >> 17) & 255;
        int r = atomicAdd(&cnt[dl], 1);
        ssrc[r0 + csum[dl] + r] = (int)(v & 0x1FFFF);   // hot 33KB range, L2-local
    }
}

// ---------------------------------------------------------------- GEMM1: hs1b[n,16](bf16) = dinv * (x @ W1)
// x is the one single-touch 205MB stream: non-temporal loads keep the edge
// lists / hs tables L2-resident for the downstream gathers.
#define G1_ROWS 256
#define G1_KC 32
__global__ __launch_bounds__(TPB) void k_gemm1(const float* __restrict__ x,
                                               const float* __restrict__ W,
                                               const float* __restrict__ dinv,
                                               unsigned short* __restrict__ hsb, int n) {
    __shared__ float xs[G1_ROWS][36];
    __shared__ float wl[G1_KC][16];
    const int tid = threadIdx.x;
    const int row0 = blockIdx.x * G1_ROWS;
    const int rg = tid >> 2;            // 0..63
    const int c0 = (tid & 3) * 4;       // 0,4,8,12

    float acc[4][4];
#pragma unroll
    for (int j = 0; j < 4; ++j)
#pragma unroll
        for (int c = 0; c < 4; ++c) acc[j][c] = 0.0f;

    for (int kc = 0; kc < 512; kc += G1_KC) {
        __syncthreads();
#pragma unroll
        for (int t = 0; t < 8; ++t) {
            int f4 = tid + TPB * t;
            int row = f4 >> 3;
            int kk = (f4 & 7) * 4;
            int grow = row0 + row;
            if (grow >= n) grow = n - 1;
            f32x4 v = __builtin_nontemporal_load(
                reinterpret_cast<const f32x4*>(&x[(size_t)grow * 512 + kc + kk]));
            *reinterpret_cast<f32x4*>(&xs[row][kk]) = v;
        }
        if (tid < 128) {
            int k = tid >> 2, cc = (tid & 3) * 4;
            *reinterpret_cast<float4*>(&wl[k][cc]) =
                *reinterpret_cast<const float4*>(&W[(size_t)(kc + k) * 16 + cc]);
        }
        __syncthreads();

#pragma unroll
        for (int k4 = 0; k4 < G1_KC; k4 += 4) {
            float w[4][4];
#pragma unroll
            for (int kk = 0; kk < 4; ++kk) {
                float4 wv = *reinterpret_cast<const float4*>(&wl[k4 + kk][c0]);
                w[kk][0] = wv.x; w[kk][1] = wv.y; w[kk][2] = wv.z; w[kk][3] = wv.w;
            }
#pragma unroll
            for (int j = 0; j < 4; ++j) {
                float4 xv = *reinterpret_cast<const float4*>(&xs[rg + 64 * j][k4]);
                float xk[4] = {xv.x, xv.y, xv.z, xv.w};
#pragma unroll
                for (int kk = 0; kk < 4; ++kk)
#pragma unroll
                    for (int c = 0; c < 4; ++c) acc[j][c] += xk[kk] * w[kk][c];
            }
        }
    }

#pragma unroll
    for (int j = 0; j < 4; ++j) {
        int grow = row0 + rg + 64 * j;
        if (grow < n) {
            float di = dinv[grow];
            ushort4 o;
            o.x = f2bf(acc[j][0] * di);
            o.y = f2bf(acc[j][1] * di);
            o.z = f2bf(acc[j][2] * di);
            o.w = f2bf(acc[j][3] * di);
            *reinterpret_cast<ushort4*>(&hsb[(size_t)grow * 16 + c0]) = o;
        }
    }
}

// ---------------------------------------------------------------- layer-1 gather-agg, bf16 rows (32B), one pass.
// Wave per node; lane = (j, hf): 32 edges in flight x 2 lanes (16B each).
// houtB = bf16( dinv * relu( dinv*(sum+self) + b ) )   (pre-scaled for layer 2)
__global__ __launch_bounds__(TPB) void k_gagg1(const int* __restrict__ rs,
                                               const int* __restrict__ ssrc,
                                               const unsigned short* __restrict__ hinB,
                                               const float* __restrict__ dinv,
                                               const float* __restrict__ b1,
                                               unsigned short* __restrict__ houtB, int n) {
    int node = blockIdx.x * 4 + (threadIdx.x >> 6);
    if (node >= n) return;
    const int lane = threadIdx.x & 63;
    const int j = lane >> 1;             // 0..31 edge sub-group
    const int hf = lane & 1;             // which 8-feature half (16B)
    const int r0 = rs[node], r1 = rs[node + 1];

    float a[8];
#pragma unroll
    for (int q = 0; q < 8; ++q) a[q] = 0.0f;

    for (int e = r0 + j; e < r1; e += 32) {
        int sv = ssrc[e];
        uint4 v = *reinterpret_cast<const uint4*>(&hinB[(size_t)sv * 16 + hf * 8]);
        a[0] += bflo(v.x); a[1] += bfhi(v.x);
        a[2] += bflo(v.y); a[3] += bfhi(v.y);
        a[4] += bflo(v.z); a[5] += bfhi(v.z);
        a[6] += bflo(v.w); a[7] += bfhi(v.w);
    }
#pragma unroll
    for (int m = 2; m <= 32; m <<= 1)
#pragma unroll
        for (int q = 0; q < 8; ++q) a[q] += __shfl_xor(a[q], m);

    if (j == 0) {
        float di = dinv[node];
        uint4 sv = *reinterpret_cast<const uint4*>(&hinB[(size_t)node * 16 + hf * 8]);
        float sf[8] = {bflo(sv.x), bfhi(sv.x), bflo(sv.y), bfhi(sv.y),
                       bflo(sv.z), bfhi(sv.z), bflo(sv.w), bfhi(sv.w)};
        unsigned short ob[8];
#pragma unroll
        for (int q = 0; q < 8; ++q) {
            float p = di * (a[q] + sf[q]);
            ob[q] = f2bf(di * fmaxf(p + b1[hf * 8 + q], 0.0f));
        }
        uint4 ov;
        ov.x = (u32)ob[0] | ((u32)ob[1] << 16);
        ov.y = (u32)ob[2] | ((u32)ob[3] << 16);
        ov.z = (u32)ob[4] | ((u32)ob[5] << 16);
        ov.w = (u32)ob[6] | ((u32)ob[7] << 16);
        *reinterpret_cast<uint4*>(&houtB[(size_t)node * 16 + hf * 8]) = ov;
    }
}

// ---------------------------------------------------------------- layer-2 gather-agg FUSED with GEMM2:
// pre[i,:] = dinv*(sum+self) staged in LDS (4 nodes/block), then
// out[i,:40] = pre[i,:16] @ W2 + b2 computed by 160 threads.
__global__ __launch_bounds__(TPB) void k_gagg2f(const int* __restrict__ rs,
                                                const int* __restrict__ ssrc,
                                                const unsigned short* __restrict__ hinB,
                                                const float* __restrict__ dinv,
                                                const float* __restrict__ W2,
                                                const float* __restrict__ b2,
                                                float* __restrict__ out, int n) {
    __shared__ float pre_l[4][17];
    __shared__ float wl[16 * 40];
    __shared__ float bl[40];
    const int tid = threadIdx.x;
    for (int i = tid; i < 640; i += TPB) wl[i] = W2[i];
    if (tid < 40) bl[tid] = b2[tid];

    const int w = tid >> 6;              // node slot 0..3
    const int node = blockIdx.x * 4 + w;
    const int lane = tid & 63;
    const int j = lane >> 1;
    const int hf = lane & 1;

    if (node < n) {
        const int r0 = rs[node], r1 = rs[node + 1];
        float a[8];
#pragma unroll
        for (int q = 0; q < 8; ++q) a[q] = 0.0f;
        for (int e = r0 + j; e < r1; e += 32) {
            int sv = ssrc[e];
            uint4 v = *reinterpret_cast<const uint4*>(&hinB[(size_t)sv * 16 + hf * 8]);
            a[0] += bflo(v.x); a[1] += bfhi(v.x);
            a[2] += bflo(v.y); a[3] += bfhi(v.y);
            a[4] += bflo(v.z); a[5] += bfhi(v.z);
            a[6] += bflo(v.w); a[7] += bfhi(v.w);
        }
#pragma unroll
        for (int m = 2; m <= 32; m <<= 1)
#pragma unroll
            for (int q = 0; q < 8; ++q) a[q] += __shfl_xor(a[q], m);
        if (j == 0) {
            float di = dinv[node];
            uint4 sv = *reinterpret_cast<const uint4*>(&hinB[(size_t)node * 16 + hf * 8]);
            float sf[8] = {bflo(sv.x), bfhi(sv.x), bflo(sv.y), bfhi(sv.y),
                           bflo(sv.z), bfhi(sv.z), bflo(sv.w), bfhi(sv.w)};
#pragma unroll
            for (int q = 0; q < 8; ++q)
                pre_l[w][hf * 8 + q] = di * (a[q] + sf[q]);
        }
    }
    __syncthreads();

    if (tid < 160) {
        int ns = tid / 40, c = tid - ns * 40;
        int gnode = blockIdx.x * 4 + ns;
        if (gnode < n) {
            float acc = bl[c];
#pragma unroll
            for (int k = 0; k < 16; ++k) acc += pre_l[ns][k] * wl[k * 40 + c];
            out[(size_t)gnode * 40 + c] = acc;
        }
    }
}

extern "C" void kernel_launch(void* const* d_in, const int* in_sizes, int n_in,
                              void* d_out, int out_size, void* d_ws, size_t ws_size,
                              hipStream_t stream) {
    const float* x  = (const float*)d_in[0];
    const int*   ei = (const int*)d_in[1];
    const float* W1 = (const float*)d_in[2];
    const float* b1 = (const float*)d_in[3];
    const float* W2 = (const float*)d_in[4];
    const float* b2 = (const float*)d_in[5];
    float* out = (float*)d_out;

    const int n = in_sizes[0] / 512;
    const int E = in_sizes[1] / 2;
    const int* src = ei;
    const int* dst = ei + E;
    const int nbkt = (n + 255) >> 8;              // 391
    const int NB1 = (E + CHUNK - 1) / CHUNK;      // 521

    // workspace layout
    char* w = (char*)d_ws;
    int*   histT   = (int*)w;     w += (size_t)NB1 * NBKT_MAX * 4;
    int*   rowtot  = (int*)w;     w += (size_t)NBKT_MAX * 4;
    int*   bktbase = (int*)w;     w += (size_t)(NBKT_MAX + 1) * 4;
    u32*   pk      = (u32*)w;     w += (size_t)E * 4;
    int*   ssrc    = (int*)w;     w += (size_t)E * 4;
    int*   rs      = (int*)w;     w += (size_t)(n + 1) * 4;
    float* dinv    = (float*)w;   w += (size_t)n * 4;
    unsigned short* h1b = (unsigned short*)w;  w += (size_t)n * 16 * 2;
    unsigned short* h2b = (unsigned short*)w;  // n*16*2

    k_hist   <<<NB1, TPB, 0, stream>>>(dst, histT, E, nbkt);
    k_scanrow<<<nbkt, 512, 0, stream>>>(histT, rowtot, NB1);
    k_scanbkt<<<1, 512, 0, stream>>>(rowtot, bktbase, rs, nbkt, n, E);
    k_part   <<<NB1, TPB, 0, stream>>>(src, dst, histT, bktbase, pk, E, nbkt);
    k_part2  <<<nbkt, TPB, 0, stream>>>(pk, bktbase, ssrc, rs, dinv, n);
    k_gemm1  <<<(n + G1_ROWS - 1) / G1_ROWS, TPB, 0, stream>>>(x, W1, dinv, h1b, n);
    k_gagg1  <<<(n + 3) / 4, TPB, 0, stream>>>(rs, ssrc, h1b, dinv, b1, h2b, n);
    k_gagg2f <<<(n + 3) / 4, TPB, 0, stream>>>(rs, ssrc, h2b, dinv, W2, b2, out, n);
}